// Round 2
// baseline (1426.036 us; speedup 1.0000x reference)
//
#include <hip/hip_runtime.h>
#include <hip/hip_bf16.h>

#define N_EDGES_C 1000000
#define EDGE_DIM_C 64
#define NODE_DIM_C 64
#define IN_DIM_C   192
#define HID_C      256
#define XPAD 200            // padded bf16 elems per X row (192+8) -> 400B rows
#define IDX_OFF 25600       // byte offset of index arrays (past Xs high-water 25584)

typedef __attribute__((ext_vector_type(8))) short  short8;
typedef __attribute__((ext_vector_type(4))) float  f32x4;

__device__ __forceinline__ unsigned short f2bf(float f) {
    union { float f; unsigned u; } v; v.f = f;
    unsigned u = v.u;
    u += 0x7fffu + ((u >> 16) & 1u);   // round-to-nearest-even
    return (unsigned short)(u >> 16);
}

// Pre-transpose + convert weights: W1[192][256] -> W1T bf16 [256][192],
// W2[256][256] -> W2T bf16 [256][256]. Tiny, runs once per launch.
__global__ void prep_weights_kernel(const float* __restrict__ W1,
                                    const float* __restrict__ W2,
                                    unsigned short* __restrict__ W1T,
                                    unsigned short* __restrict__ W2T) {
    int tid = blockIdx.x * 256 + threadIdx.x;
    if (tid < IN_DIM_C * HID_C) {
        int n = tid / IN_DIM_C, k = tid - n * IN_DIM_C;
        W1T[tid] = f2bf(W1[k * HID_C + n]);
    } else {
        int t2 = tid - IN_DIM_C * HID_C;
        if (t2 < HID_C * HID_C) {
            int o = t2 / HID_C, k = t2 - o * HID_C;
            W2T[t2] = f2bf(W2[k * HID_C + o]);
        }
    }
}

// One block = 64 edges, 4 waves; wave w owns feature slice [w*64, w*64+64).
// LDS: single 32768B buffer.
//   Phase A (staging + L1): Xs = [64][XPAD] bf16 at offset 0 (25.6KB),
//                           sidx/didx (512B) at offset 25600.
//   Phase B (L2):           Hs = [64][256] bf16, XOR-swizzled, full 32KB.
// Hs address: byte = m*512 + (2*n ^ ((m&15)<<4))  -- bank-conflict-free.
__global__ __launch_bounds__(256, 5) void edge_mlp_kernel(
    const float* __restrict__ E, const float* __restrict__ V,
    const int* __restrict__ srcI, const int* __restrict__ dstI,
    const unsigned short* __restrict__ W1T, const float* __restrict__ b1,
    const unsigned short* __restrict__ W2T, const float* __restrict__ b2,
    float* __restrict__ out)
{
    __shared__ unsigned char smem[32768];
    unsigned short* Xs  = (unsigned short*)smem;
    int*            sidx = (int*)(smem + IDX_OFF);
    int*            didx = sidx + 64;

    const int tid  = threadIdx.x;
    const int base = blockIdx.x * 64;

    // --- preload gather indices (into aliased region, dead after staging) ---
    if (tid < 64)        sidx[tid]      = srcI[base + tid];
    else if (tid < 128)  didx[tid - 64] = dstI[base + tid - 64];

    // --- stage E (64 rows x 64 fp32, coalesced float4) ---
#pragma unroll
    for (int i = 0; i < 4; ++i) {
        int idx = tid + i * 256;        // 0..1023 float4s
        int r = idx >> 4, c4 = idx & 15;
        float4 v = *reinterpret_cast<const float4*>(
            E + (size_t)(base + r) * EDGE_DIM_C + c4 * 4);
        ushort4 b;
        b.x = f2bf(v.x); b.y = f2bf(v.y); b.z = f2bf(v.z); b.w = f2bf(v.w);
        *reinterpret_cast<ushort4*>(&Xs[r * XPAD + c4 * 4]) = b;
    }
    __syncthreads();   // indices visible

    // --- stage V[src], V[dst] gathers (64 rows x 128 fp32) ---
#pragma unroll
    for (int i = 0; i < 8; ++i) {
        int idx = tid + i * 256;        // 0..2047 float4s
        int r = idx >> 5, c4 = idx & 31;
        int col = c4 * 4;
        const float* vp = (col < 64)
            ? (V + (size_t)sidx[r] * NODE_DIM_C + col)
            : (V + (size_t)didx[r] * NODE_DIM_C + (col - 64));
        float4 v = *reinterpret_cast<const float4*>(vp);
        ushort4 b;
        b.x = f2bf(v.x); b.y = f2bf(v.y); b.z = f2bf(v.z); b.w = f2bf(v.w);
        *reinterpret_cast<ushort4*>(&Xs[r * XPAD + 64 + col]) = b;
    }
    __syncthreads();

    const int w  = tid >> 6;    // wave id 0..3
    const int l  = tid & 63;
    const int lm = l & 15;      // A-row / B-row lane index
    const int lg = l >> 4;      // k-group / D-row group

    // ---------------- Layer 1 ----------------
    f32x4 acc[4][4];            // [ntile][mtile]
#pragma unroll
    for (int a = 0; a < 4; ++a)
#pragma unroll
        for (int b = 0; b < 4; ++b)
            acc[a][b] = (f32x4){0.f, 0.f, 0.f, 0.f};

    const unsigned short* w1base = W1T + (size_t)(w * 64) * IN_DIM_C;
#pragma unroll
    for (int kb = 0; kb < 6; ++kb) {
        short8 aw[4], bx[4];
#pragma unroll
        for (int nt = 0; nt < 4; ++nt)
            aw[nt] = *reinterpret_cast<const short8*>(
                w1base + (nt * 16 + lm) * IN_DIM_C + kb * 32 + lg * 8);
#pragma unroll
        for (int mt = 0; mt < 4; ++mt)
            bx[mt] = *reinterpret_cast<const short8*>(
                &Xs[(mt * 16 + lm) * XPAD + kb * 32 + lg * 8]);
#pragma unroll
        for (int nt = 0; nt < 4; ++nt)
#pragma unroll
            for (int mt = 0; mt < 4; ++mt)
                acc[nt][mt] = __builtin_amdgcn_mfma_f32_16x16x32_bf16(
                    aw[nt], bx[mt], acc[nt][mt], 0, 0, 0);
    }

    __syncthreads();   // all waves done reading Xs before Hs overwrites it

    // epilogue 1: + b1, relu, bf16 -> Hs (swizzled, aliases Xs)
#pragma unroll
    for (int nt = 0; nt < 4; ++nt) {
        int n0 = w * 64 + nt * 16 + lg * 4;
        float4 bv = *reinterpret_cast<const float4*>(b1 + n0);
#pragma unroll
        for (int mt = 0; mt < 4; ++mt) {
            f32x4 a = acc[nt][mt];
            ushort4 hb;
            hb.x = f2bf(fmaxf(a[0] + bv.x, 0.f));
            hb.y = f2bf(fmaxf(a[1] + bv.y, 0.f));
            hb.z = f2bf(fmaxf(a[2] + bv.z, 0.f));
            hb.w = f2bf(fmaxf(a[3] + bv.w, 0.f));
            int m = mt * 16 + lm;
            int addr = m * 512 + ((n0 * 2) ^ (lm << 4));
            *reinterpret_cast<ushort4*>(smem + addr) = hb;
        }
    }
    __syncthreads();

    // ---------------- Layer 2 ----------------
#pragma unroll
    for (int a = 0; a < 4; ++a)
#pragma unroll
        for (int b = 0; b < 4; ++b)
            acc[a][b] = (f32x4){0.f, 0.f, 0.f, 0.f};

    const unsigned short* w2base = W2T + (size_t)(w * 64) * HID_C;
#pragma unroll
    for (int kb = 0; kb < 8; ++kb) {
        short8 aw[4], bh[4];
#pragma unroll
        for (int ot = 0; ot < 4; ++ot)
            aw[ot] = *reinterpret_cast<const short8*>(
                w2base + (ot * 16 + lm) * HID_C + kb * 32 + lg * 8);
#pragma unroll
        for (int mt = 0; mt < 4; ++mt) {
            int m = mt * 16 + lm;
            int addr = m * 512 + (((kb * 32 + lg * 8) * 2) ^ (lm << 4));
            bh[mt] = *reinterpret_cast<const short8*>(smem + addr);
        }
#pragma unroll
        for (int ot = 0; ot < 4; ++ot)
#pragma unroll
            for (int mt = 0; mt < 4; ++mt)
                acc[ot][mt] = __builtin_amdgcn_mfma_f32_16x16x32_bf16(
                    aw[ot], bh[mt], acc[ot][mt], 0, 0, 0);
    }

    // epilogue 2: + b2, coalesced nontemporal float4 store
#pragma unroll
    for (int ot = 0; ot < 4; ++ot) {
        int o0 = w * 64 + ot * 16 + lg * 4;
        float4 bv = *reinterpret_cast<const float4*>(b2 + o0);
#pragma unroll
        for (int mt = 0; mt < 4; ++mt) {
            f32x4 a = acc[ot][mt];
            f32x4 r;
            r[0] = a[0] + bv.x;
            r[1] = a[1] + bv.y;
            r[2] = a[2] + bv.z;
            r[3] = a[3] + bv.w;
            size_t m = (size_t)(base + mt * 16 + lm);
            __builtin_nontemporal_store(
                r, reinterpret_cast<f32x4*>(out + m * HID_C + o0));
        }
    }
}

extern "C" void kernel_launch(void* const* d_in, const int* in_sizes, int n_in,
                              void* d_out, int out_size, void* d_ws, size_t ws_size,
                              hipStream_t stream) {
    const float* E  = (const float*)d_in[0];
    const float* V  = (const float*)d_in[1];
    const int*   ei = (const int*)d_in[2];   // [2][N_EDGES] int32
    const float* W1 = (const float*)d_in[3];
    const float* b1 = (const float*)d_in[4];
    const float* W2 = (const float*)d_in[5];
    const float* b2 = (const float*)d_in[6];
    float* out = (float*)d_out;

    unsigned short* W1T = (unsigned short*)d_ws;                 // 256*192 bf16
    unsigned short* W2T = W1T + IN_DIM_C * HID_C;                // 256*256 bf16

    const int prep_total = IN_DIM_C * HID_C + HID_C * HID_C;     // 114688
    prep_weights_kernel<<<(prep_total + 255) / 256, 256, 0, stream>>>(W1, W2, W1T, W2T);

    const int nblocks = N_EDGES_C / 64;                          // 15625
    edge_mlp_kernel<<<nblocks, 256, 0, stream>>>(
        E, V, ei, ei + N_EDGES_C, W1T, b1, W2T, b2, out);
}

// Round 3
// 673.668 us; speedup vs baseline: 2.1168x; 2.1168x over previous
//
#include <hip/hip_runtime.h>
#include <hip/hip_bf16.h>

#define N_EDGES_C 1000000
#define EDGE_DIM_C 64
#define NODE_DIM_C 64
#define IN_DIM_C   192
#define HID_C      256
#define XPAD 200            // padded bf16 elems per X row (192+8) -> 400B rows
#define IDX_OFF 25600       // byte offset of index arrays (past Xs high-water 25584)

typedef __attribute__((ext_vector_type(8))) short  short8;
typedef __attribute__((ext_vector_type(4))) float  f32x4;

__device__ __forceinline__ unsigned short f2bf(float f) {
    union { float f; unsigned u; } v; v.f = f;
    unsigned u = v.u;
    u += 0x7fffu + ((u >> 16) & 1u);   // round-to-nearest-even
    return (unsigned short)(u >> 16);
}

// Pre-transpose + convert weights: W1[192][256] -> W1T bf16 [256][192],
// W2[256][256] -> W2T bf16 [256][256]. Tiny, runs once per launch.
__global__ void prep_weights_kernel(const float* __restrict__ W1,
                                    const float* __restrict__ W2,
                                    unsigned short* __restrict__ W1T,
                                    unsigned short* __restrict__ W2T) {
    int tid = blockIdx.x * 256 + threadIdx.x;
    if (tid < IN_DIM_C * HID_C) {
        int n = tid / IN_DIM_C, k = tid - n * IN_DIM_C;
        W1T[tid] = f2bf(W1[k * HID_C + n]);
    } else {
        int t2 = tid - IN_DIM_C * HID_C;
        if (t2 < HID_C * HID_C) {
            int o = t2 / HID_C, k = t2 - o * HID_C;
            W2T[t2] = f2bf(W2[k * HID_C + o]);
        }
    }
}

// One block = 64 edges, 4 waves; wave w owns feature slice [w*64, w*64+64).
// LDS: single 32768B buffer (5 blocks/CU fit).
//   Phase A (staging + L1): Xs = [64][XPAD] bf16 at offset 0 (25.6KB),
//                           sidx/didx (512B) at offset 25600.
//   Phase B (L2):           Hs = [64][256] bf16, XOR-swizzled, full 32KB.
// Hs address: byte = m*512 + (2*n ^ ((m&15)<<4))  -- bank-conflict-free.
// launch_bounds(256,4): 128-VGPR cap >> natural ~88 use. (256,5) caps at 102
// and spilled the MFMA accumulators to scratch: +3GB write traffic, 2x slower.
__global__ __launch_bounds__(256, 4) void edge_mlp_kernel(
    const float* __restrict__ E, const float* __restrict__ V,
    const int* __restrict__ srcI, const int* __restrict__ dstI,
    const unsigned short* __restrict__ W1T, const float* __restrict__ b1,
    const unsigned short* __restrict__ W2T, const float* __restrict__ b2,
    float* __restrict__ out)
{
    __shared__ unsigned char smem[32768];
    unsigned short* Xs  = (unsigned short*)smem;
    int*            sidx = (int*)(smem + IDX_OFF);
    int*            didx = sidx + 64;

    const int tid  = threadIdx.x;
    const int base = blockIdx.x * 64;

    // --- preload gather indices (into aliased region, dead after staging) ---
    if (tid < 64)        sidx[tid]      = srcI[base + tid];
    else if (tid < 128)  didx[tid - 64] = dstI[base + tid - 64];

    // --- stage E (64 rows x 64 fp32, coalesced float4) ---
#pragma unroll
    for (int i = 0; i < 4; ++i) {
        int idx = tid + i * 256;        // 0..1023 float4s
        int r = idx >> 4, c4 = idx & 15;
        float4 v = *reinterpret_cast<const float4*>(
            E + (size_t)(base + r) * EDGE_DIM_C + c4 * 4);
        ushort4 b;
        b.x = f2bf(v.x); b.y = f2bf(v.y); b.z = f2bf(v.z); b.w = f2bf(v.w);
        *reinterpret_cast<ushort4*>(&Xs[r * XPAD + c4 * 4]) = b;
    }
    __syncthreads();   // indices visible

    // --- stage V[src], V[dst] gathers (64 rows x 128 fp32) ---
#pragma unroll
    for (int i = 0; i < 8; ++i) {
        int idx = tid + i * 256;        // 0..2047 float4s
        int r = idx >> 5, c4 = idx & 31;
        int col = c4 * 4;
        const float* vp = (col < 64)
            ? (V + (size_t)sidx[r] * NODE_DIM_C + col)
            : (V + (size_t)didx[r] * NODE_DIM_C + (col - 64));
        float4 v = *reinterpret_cast<const float4*>(vp);
        ushort4 b;
        b.x = f2bf(v.x); b.y = f2bf(v.y); b.z = f2bf(v.z); b.w = f2bf(v.w);
        *reinterpret_cast<ushort4*>(&Xs[r * XPAD + 64 + col]) = b;
    }
    __syncthreads();

    const int w  = tid >> 6;    // wave id 0..3
    const int l  = tid & 63;
    const int lm = l & 15;      // A-row / B-row lane index
    const int lg = l >> 4;      // k-group / D-row group

    // ---------------- Layer 1 ----------------
    f32x4 acc[4][4];            // [ntile][mtile]
#pragma unroll
    for (int a = 0; a < 4; ++a)
#pragma unroll
        for (int b = 0; b < 4; ++b)
            acc[a][b] = (f32x4){0.f, 0.f, 0.f, 0.f};

    const unsigned short* w1base = W1T + (size_t)(w * 64) * IN_DIM_C;
#pragma unroll
    for (int kb = 0; kb < 6; ++kb) {
        short8 aw[4], bx[4];
#pragma unroll
        for (int nt = 0; nt < 4; ++nt)
            aw[nt] = *reinterpret_cast<const short8*>(
                w1base + (nt * 16 + lm) * IN_DIM_C + kb * 32 + lg * 8);
#pragma unroll
        for (int mt = 0; mt < 4; ++mt)
            bx[mt] = *reinterpret_cast<const short8*>(
                &Xs[(mt * 16 + lm) * XPAD + kb * 32 + lg * 8]);
#pragma unroll
        for (int nt = 0; nt < 4; ++nt)
#pragma unroll
            for (int mt = 0; mt < 4; ++mt)
                acc[nt][mt] = __builtin_amdgcn_mfma_f32_16x16x32_bf16(
                    aw[nt], bx[mt], acc[nt][mt], 0, 0, 0);
    }

    __syncthreads();   // all waves done reading Xs before Hs overwrites it

    // epilogue 1: + b1, relu, bf16 -> Hs (swizzled, aliases Xs)
#pragma unroll
    for (int nt = 0; nt < 4; ++nt) {
        int n0 = w * 64 + nt * 16 + lg * 4;
        float4 bv = *reinterpret_cast<const float4*>(b1 + n0);
#pragma unroll
        for (int mt = 0; mt < 4; ++mt) {
            f32x4 a = acc[nt][mt];
            ushort4 hb;
            hb.x = f2bf(fmaxf(a[0] + bv.x, 0.f));
            hb.y = f2bf(fmaxf(a[1] + bv.y, 0.f));
            hb.z = f2bf(fmaxf(a[2] + bv.z, 0.f));
            hb.w = f2bf(fmaxf(a[3] + bv.w, 0.f));
            int m = mt * 16 + lm;
            int addr = m * 512 + ((n0 * 2) ^ (lm << 4));
            *reinterpret_cast<ushort4*>(smem + addr) = hb;
        }
    }
    __syncthreads();

    // ---------------- Layer 2 ----------------
#pragma unroll
    for (int a = 0; a < 4; ++a)
#pragma unroll
        for (int b = 0; b < 4; ++b)
            acc[a][b] = (f32x4){0.f, 0.f, 0.f, 0.f};

    const unsigned short* w2base = W2T + (size_t)(w * 64) * HID_C;
#pragma unroll
    for (int kb = 0; kb < 8; ++kb) {
        short8 aw[4], bh[4];
#pragma unroll
        for (int ot = 0; ot < 4; ++ot)
            aw[ot] = *reinterpret_cast<const short8*>(
                w2base + (ot * 16 + lm) * HID_C + kb * 32 + lg * 8);
#pragma unroll
        for (int mt = 0; mt < 4; ++mt) {
            int m = mt * 16 + lm;
            int addr = m * 512 + (((kb * 32 + lg * 8) * 2) ^ (lm << 4));
            bh[mt] = *reinterpret_cast<const short8*>(smem + addr);
        }
#pragma unroll
        for (int ot = 0; ot < 4; ++ot)
#pragma unroll
            for (int mt = 0; mt < 4; ++mt)
                acc[ot][mt] = __builtin_amdgcn_mfma_f32_16x16x32_bf16(
                    aw[ot], bh[mt], acc[ot][mt], 0, 0, 0);
    }

    // epilogue 2: + b2, coalesced nontemporal float4 store
#pragma unroll
    for (int ot = 0; ot < 4; ++ot) {
        int o0 = w * 64 + ot * 16 + lg * 4;
        float4 bv = *reinterpret_cast<const float4*>(b2 + o0);
#pragma unroll
        for (int mt = 0; mt < 4; ++mt) {
            f32x4 a = acc[ot][mt];
            f32x4 r;
            r[0] = a[0] + bv.x;
            r[1] = a[1] + bv.y;
            r[2] = a[2] + bv.z;
            r[3] = a[3] + bv.w;
            size_t m = (size_t)(base + mt * 16 + lm);
            __builtin_nontemporal_store(
                r, reinterpret_cast<f32x4*>(out + m * HID_C + o0));
        }
    }
}

extern "C" void kernel_launch(void* const* d_in, const int* in_sizes, int n_in,
                              void* d_out, int out_size, void* d_ws, size_t ws_size,
                              hipStream_t stream) {
    const float* E  = (const float*)d_in[0];
    const float* V  = (const float*)d_in[1];
    const int*   ei = (const int*)d_in[2];   // [2][N_EDGES] int32
    const float* W1 = (const float*)d_in[3];
    const float* b1 = (const float*)d_in[4];
    const float* W2 = (const float*)d_in[5];
    const float* b2 = (const float*)d_in[6];
    float* out = (float*)d_out;

    unsigned short* W1T = (unsigned short*)d_ws;                 // 256*192 bf16
    unsigned short* W2T = W1T + IN_DIM_C * HID_C;                // 256*256 bf16

    const int prep_total = IN_DIM_C * HID_C + HID_C * HID_C;     // 114688
    prep_weights_kernel<<<(prep_total + 255) / 256, 256, 0, stream>>>(W1, W2, W1T, W2T);

    const int nblocks = N_EDGES_C / 64;                          // 15625
    edge_mlp_kernel<<<nblocks, 256, 0, stream>>>(
        E, V, ei, ei + N_EDGES_C, W1T, b1, W2T, b2, out);
}

// Round 4
// 507.725 us; speedup vs baseline: 2.8087x; 1.3268x over previous
//
#include <hip/hip_runtime.h>
#include <hip/hip_bf16.h>

#define N_EDGES_C 1000000
#define EDGE_DIM_C 64
#define NODE_DIM_C 64
#define IN_DIM_C   192
#define HID_C      256
#define XPAD 200            // bf16 elems per X row (192+8 pad) -> 400B rows
#define HS_OFF 25600        // byte offset of swizzled H region (Xs high-water 25576)
#define T_TILES 5           // tiles (of 64 edges) per block; 15625/5 = 3125 blocks

typedef __attribute__((ext_vector_type(8))) short  short8;
typedef __attribute__((ext_vector_type(4))) float  f32x4;

__device__ __forceinline__ unsigned short f2bf(float f) {
    union { float f; unsigned u; } v; v.f = f;
    unsigned u = v.u;
    u += 0x7fffu + ((u >> 16) & 1u);   // round-to-nearest-even
    return (unsigned short)(u >> 16);
}

// W1[192][256] -> W1T bf16 [256][192]; W2[256][256] -> W2T bf16 [256][256].
__global__ void prep_weights_kernel(const float* __restrict__ W1,
                                    const float* __restrict__ W2,
                                    unsigned short* __restrict__ W1T,
                                    unsigned short* __restrict__ W2T) {
    int tid = blockIdx.x * 256 + threadIdx.x;
    if (tid < IN_DIM_C * HID_C) {
        int n = tid / IN_DIM_C, k = tid - n * IN_DIM_C;
        W1T[tid] = f2bf(W1[k * HID_C + n]);
    } else {
        int t2 = tid - IN_DIM_C * HID_C;
        if (t2 < HID_C * HID_C) {
            int o = t2 / HID_C, k = t2 - o * HID_C;
            W2T[t2] = f2bf(W2[k * HID_C + o]);
        }
    }
}

// 512 threads = 8 waves. Wave w owns feature slice [w*32, w*32+32) for BOTH
// layers; its W1/W2 fragments are preloaded into registers ONCE per block
// (112 VGPR) so the tile loop has no global weight loads.
// Each block processes T_TILES tiles of 64 edges, software-pipelined:
//   issue(t+1) gathers -> regs | L1 MFMA(t) | bar | write_lds(t+1)+epi1(t) |
//   bar | L2 MFMA(t) + store(t)
// Gather loads stay in flight across the barriers (reg-staged, T14).
__global__ __launch_bounds__(512, 2) void edge_mlp_kernel(
    const float* __restrict__ E, const float* __restrict__ V,
    const int* __restrict__ srcI, const int* __restrict__ dstI,
    const unsigned short* __restrict__ W1T, const float* __restrict__ b1,
    const unsigned short* __restrict__ W2T, const float* __restrict__ b2,
    float* __restrict__ out)
{
    __shared__ unsigned char smem[HS_OFF + 32768];   // 58368 B -> 1-2 blocks/CU
    unsigned short* Xs = (unsigned short*)smem;      // [64][XPAD] bf16

    const int tid = threadIdx.x;
    const int w  = tid >> 6;     // wave 0..7
    const int l  = tid & 63;
    const int lm = l & 15;
    const int lg = l >> 4;
    const long block0 = (long)blockIdx.x * (64 * T_TILES);

    // ---- weight fragments -> registers (once per block; L1/L2-cache hot) ----
    short8 wA1[6][2];            // [kb][nt] : W1T rows w*32+nt*16+lm, k=kb*32+lg*8
    short8 wA2[8][2];            // [kb][ot] : W2T rows w*32+ot*16+lm
#pragma unroll
    for (int kb = 0; kb < 6; ++kb)
#pragma unroll
        for (int nt = 0; nt < 2; ++nt)
            wA1[kb][nt] = *reinterpret_cast<const short8*>(
                W1T + (size_t)(w * 32 + nt * 16 + lm) * IN_DIM_C + kb * 32 + lg * 8);
#pragma unroll
    for (int kb = 0; kb < 8; ++kb)
#pragma unroll
        for (int ot = 0; ot < 2; ++ot)
            wA2[kb][ot] = *reinterpret_cast<const short8*>(
                W2T + (size_t)(w * 32 + ot * 16 + lm) * HID_C + kb * 32 + lg * 8);

    // ---- reg-staged next-tile data (lives across barriers) ----
    float4 fE[2];   // wave's 8 E-rows x 64 f32: 2 float4/lane
    float4 fV[4];   // wave's 8 (src,dst) V-rows: 4 float4/lane

    // Issue global loads for tile at base tb (wave-local rows [w*8, w*8+8)).
    auto issue = [&](long tb) {
        int kind = (l >> 3) & 1;                 // 0:src 1:dst
        int rr   = l & 7;
        const int* ip = kind ? dstI : srcI;
        int myidx = ip[tb + w * 8 + rr];         // lanes 0-15 hold s[0..7],d[0..7]
#pragma unroll
        for (int i = 0; i < 2; ++i) {
            int f = i * 64 + l;                  // rE = f>>4 in 0..7
            fE[i] = *reinterpret_cast<const float4*>(
                E + (size_t)(tb + w * 8 + (f >> 4)) * EDGE_DIM_C + (f & 15) * 4);
        }
#pragma unroll
        for (int i = 0; i < 4; ++i) {
            int kind2 = ((l & 31) < 16) ? 0 : 1; // src / dst half of X row
            int srcl  = kind2 * 8 + i * 2 + (l >> 5);
            int gi = __builtin_amdgcn_ds_bpermute(srcl << 2, myidx); // wave-local
            fV[i] = *reinterpret_cast<const float4*>(
                V + (size_t)gi * NODE_DIM_C + (l & 15) * 4);
        }
    };

    // Convert staged regs -> bf16, write Xs. (Compiler waits vmcnt here.)
    auto write_lds = [&]() {
#pragma unroll
        for (int i = 0; i < 2; ++i) {
            int f = i * 64 + l;
            ushort4 b;
            b.x = f2bf(fE[i].x); b.y = f2bf(fE[i].y);
            b.z = f2bf(fE[i].z); b.w = f2bf(fE[i].w);
            *reinterpret_cast<ushort4*>(
                &Xs[(w * 8 + (f >> 4)) * XPAD + (f & 15) * 4]) = b;
        }
#pragma unroll
        for (int i = 0; i < 4; ++i) {
            int kind2 = ((l & 31) < 16) ? 0 : 1;
            int rV    = i * 2 + (l >> 5);
            ushort4 b;
            b.x = f2bf(fV[i].x); b.y = f2bf(fV[i].y);
            b.z = f2bf(fV[i].z); b.w = f2bf(fV[i].w);
            *reinterpret_cast<ushort4*>(
                &Xs[(w * 8 + rV) * XPAD + 64 + kind2 * 64 + (l & 15) * 4]) = b;
        }
    };

    // ---- prologue: stage tile 0 ----
    issue(block0);
    write_lds();
    __syncthreads();

#pragma unroll 1
    for (int t = 0; t < T_TILES; ++t) {
        const long tb = block0 + t * 64;
        if (t + 1 < T_TILES) issue(tb + 64);     // prefetch flies under L1/L2 MFMA

        // ---------------- Layer 1 (pure reg + LDS) ----------------
        f32x4 acc[2][4];
#pragma unroll
        for (int a = 0; a < 2; ++a)
#pragma unroll
            for (int b = 0; b < 4; ++b)
                acc[a][b] = (f32x4){0.f, 0.f, 0.f, 0.f};

#pragma unroll
        for (int kb = 0; kb < 6; ++kb) {
            short8 bx[4];
#pragma unroll
            for (int mt = 0; mt < 4; ++mt)
                bx[mt] = *reinterpret_cast<const short8*>(
                    &Xs[(mt * 16 + lm) * XPAD + kb * 32 + lg * 8]);
#pragma unroll
            for (int nt = 0; nt < 2; ++nt)
#pragma unroll
                for (int mt = 0; mt < 4; ++mt)
                    acc[nt][mt] = __builtin_amdgcn_mfma_f32_16x16x32_bf16(
                        wA1[kb][nt], bx[mt], acc[nt][mt], 0, 0, 0);
        }
        __syncthreads();                 // (1) all waves done reading Xs(t)

        if (t + 1 < T_TILES) write_lds();        // Xs(t+1)

        // epi1: +b1, relu, bf16 -> Hs (XOR-swizzled region at HS_OFF)
#pragma unroll
        for (int nt = 0; nt < 2; ++nt) {
            int n0 = w * 32 + nt * 16 + lg * 4;
            float4 bv = *reinterpret_cast<const float4*>(b1 + n0);
#pragma unroll
            for (int mt = 0; mt < 4; ++mt) {
                f32x4 a = acc[nt][mt];
                ushort4 hb;
                hb.x = f2bf(fmaxf(a[0] + bv.x, 0.f));
                hb.y = f2bf(fmaxf(a[1] + bv.y, 0.f));
                hb.z = f2bf(fmaxf(a[2] + bv.z, 0.f));
                hb.w = f2bf(fmaxf(a[3] + bv.w, 0.f));
                int m = mt * 16 + lm;
                int addr = m * 512 + ((n0 * 2) ^ (lm << 4));
                *reinterpret_cast<ushort4*>(smem + HS_OFF + addr) = hb;
            }
        }
        __syncthreads();                 // (2) Xs(t+1) + Hs(t) ready

        // ---------------- Layer 2 (pure reg + LDS) ----------------
#pragma unroll
        for (int a = 0; a < 2; ++a)
#pragma unroll
            for (int b = 0; b < 4; ++b)
                acc[a][b] = (f32x4){0.f, 0.f, 0.f, 0.f};

#pragma unroll
        for (int kb = 0; kb < 8; ++kb) {
            short8 bh[4];
#pragma unroll
            for (int mt = 0; mt < 4; ++mt) {
                int m = mt * 16 + lm;
                int addr = m * 512 + (((kb * 32 + lg * 8) * 2) ^ (lm << 4));
                bh[mt] = *reinterpret_cast<const short8*>(smem + HS_OFF + addr);
            }
#pragma unroll
            for (int ot = 0; ot < 2; ++ot)
#pragma unroll
                for (int mt = 0; mt < 4; ++mt)
                    acc[ot][mt] = __builtin_amdgcn_mfma_f32_16x16x32_bf16(
                        wA2[kb][ot], bh[mt], acc[ot][mt], 0, 0, 0);
        }

        // epi2: +b2, coalesced NT float4 store
#pragma unroll
        for (int ot = 0; ot < 2; ++ot) {
            int o0 = w * 32 + ot * 16 + lg * 4;
            float4 bv = *reinterpret_cast<const float4*>(b2 + o0);
#pragma unroll
            for (int mt = 0; mt < 4; ++mt) {
                f32x4 a = acc[ot][mt];
                f32x4 r;
                r[0] = a[0] + bv.x;
                r[1] = a[1] + bv.y;
                r[2] = a[2] + bv.z;
                r[3] = a[3] + bv.w;
                __builtin_nontemporal_store(r, reinterpret_cast<f32x4*>(
                    out + (size_t)(tb + mt * 16 + lm) * HID_C + o0));
            }
        }
    }
}

extern "C" void kernel_launch(void* const* d_in, const int* in_sizes, int n_in,
                              void* d_out, int out_size, void* d_ws, size_t ws_size,
                              hipStream_t stream) {
    const float* E  = (const float*)d_in[0];
    const float* V  = (const float*)d_in[1];
    const int*   ei = (const int*)d_in[2];   // [2][N_EDGES] int32
    const float* W1 = (const float*)d_in[3];
    const float* b1 = (const float*)d_in[4];
    const float* W2 = (const float*)d_in[5];
    const float* b2 = (const float*)d_in[6];
    float* out = (float*)d_out;

    unsigned short* W1T = (unsigned short*)d_ws;                 // 256*192 bf16
    unsigned short* W2T = W1T + IN_DIM_C * HID_C;                // 256*256 bf16

    const int prep_total = IN_DIM_C * HID_C + HID_C * HID_C;     // 114688
    prep_weights_kernel<<<(prep_total + 255) / 256, 256, 0, stream>>>(W1, W2, W1T, W2T);

    const int nblocks = N_EDGES_C / (64 * T_TILES);              // 3125
    edge_mlp_kernel<<<nblocks, 512, 0, stream>>>(
        E, V, ei, ei + N_EDGES_C, W1T, b1, W2T, b2, out);
}